// Round 2
// baseline (7380.288 us; speedup 1.0000x reference)
//
#include <hip/hip_runtime.h>

#define NROWS 65536

// ---------------------------------------------------------------------------
// Generic fp32 GEMM: C[rows,Nout] = act( concat(A1,A2)[rows,Kin] @ W + b )
// BM=64, BN=64, BK=32, 256 threads, 4x4 outputs/thread.
// A staged TRANSPOSED in LDS (stride 68 floats) -> A fragment = ds_read_b128;
// W staged row-major (stride 64) -> W fragment = ds_read_b128.
// ---------------------------------------------------------------------------
__global__ __launch_bounds__(256)
void gemm_f32(const float* __restrict__ A1, int w1,
              const float* __restrict__ A2, int w2,
              const float* __restrict__ W, const float* __restrict__ bias,
              float* __restrict__ C, int Kin, int Nout, int do_relu)
{
    __shared__ float As[32 * 68];   // [k][row]
    __shared__ float Ws[32 * 64];   // [k][col]

    const int t  = threadIdx.x;
    const int tr = t & 15;
    const int tc = t >> 4;
    const int rbase = blockIdx.y * 64;
    const int cbase = blockIdx.x * 64;

    float4 acc[4];
    #pragma unroll
    for (int i = 0; i < 4; ++i) acc[i] = make_float4(0.f, 0.f, 0.f, 0.f);

    for (int kb = 0; kb < Kin; kb += 32) {
        #pragma unroll
        for (int jj = 0; jj < 2; ++jj) {
            int f    = t + 256 * jj;        // 0..511
            int arow = f >> 3;              // 0..63
            int k4   = (f & 7) << 2;        // 0,4,..,28
            int gc   = kb + k4;
            float4 v;
            if (gc < w1) v = *(const float4*)(A1 + (size_t)(rbase + arow) * w1 + gc);
            else         v = *(const float4*)(A2 + (size_t)(rbase + arow) * w2 + (gc - w1));
            As[(k4 + 0) * 68 + arow] = v.x;
            As[(k4 + 1) * 68 + arow] = v.y;
            As[(k4 + 2) * 68 + arow] = v.z;
            As[(k4 + 3) * 68 + arow] = v.w;
        }
        #pragma unroll
        for (int jj = 0; jj < 2; ++jj) {
            int f    = t + 256 * jj;        // 0..511
            int wrow = f >> 4;              // 0..31
            int c4   = (f & 15) << 2;       // 0..60
            int gc   = cbase + c4;
            float4 v = make_float4(0.f, 0.f, 0.f, 0.f);
            if (gc + 3 < Nout) v = *(const float4*)(W + (size_t)(kb + wrow) * Nout + gc);
            *(float4*)&Ws[wrow * 64 + c4] = v;
        }
        __syncthreads();
        #pragma unroll 8
        for (int kk = 0; kk < 32; ++kk) {
            float4 a = *(float4*)&As[kk * 68 + tr * 4];
            float4 b = *(float4*)&Ws[kk * 64 + tc * 4];
            acc[0].x += a.x * b.x; acc[0].y += a.x * b.y; acc[0].z += a.x * b.z; acc[0].w += a.x * b.w;
            acc[1].x += a.y * b.x; acc[1].y += a.y * b.y; acc[1].z += a.y * b.z; acc[1].w += a.y * b.w;
            acc[2].x += a.z * b.x; acc[2].y += a.z * b.y; acc[2].z += a.z * b.z; acc[2].w += a.z * b.w;
            acc[3].x += a.w * b.x; acc[3].y += a.w * b.y; acc[3].z += a.w * b.z; acc[3].w += a.w * b.w;
        }
        __syncthreads();
    }

    const int col4 = cbase + tc * 4;
    const bool cok = (col4 + 3) < Nout;
    float4 b4 = make_float4(0.f, 0.f, 0.f, 0.f);
    if (cok) b4 = *(const float4*)(bias + col4);
    #pragma unroll
    for (int i = 0; i < 4; ++i) {
        float4 v = acc[i];
        v.x += b4.x; v.y += b4.y; v.z += b4.z; v.w += b4.w;
        if (do_relu) {
            v.x = fmaxf(v.x, 0.f); v.y = fmaxf(v.y, 0.f);
            v.z = fmaxf(v.z, 0.f); v.w = fmaxf(v.w, 0.f);
        }
        int row = rbase + tr * 4 + i;
        if (cok) *(float4*)(C + (size_t)row * Nout + col4) = v;
    }
}

// ---------------------------------------------------------------------------
__global__ __launch_bounds__(256)
void cbnorm_kernel(const float* __restrict__ cb, float* __restrict__ cbn)
{
    int code = blockIdx.x * 256 + threadIdx.x;      // 0..8191
    const float* p = cb + (size_t)code * 128;
    float s = 0.f;
    #pragma unroll 8
    for (int d4 = 0; d4 < 32; ++d4) {
        float4 v = *(const float4*)(p + d4 * 4);
        s += v.x * v.x + v.y * v.y + v.z * v.z + v.w * v.w;
    }
    cbn[code] = s;
}

// ---------------------------------------------------------------------------
// Fused residual VQ. 64 rows/block in LDS; codebook streamed in 32-code
// chunks (LDS total 59 KB < 64 KB). d = ||cb||^2 - 2 r.cb ; first-occurrence
// argmin; r -= cb[idx]; finally zhat = z - r written IN PLACE over z.
// ---------------------------------------------------------------------------
__global__ __launch_bounds__(256)
void rvq_kernel(float* __restrict__ z, const float* __restrict__ zp,
                const float* __restrict__ codebooks, const float* __restrict__ cbn,
                float* __restrict__ zhat /* may alias z */)
{
    __shared__ float r_lds[64 * 132];
    __shared__ float cbs[32 * 132];
    __shared__ float minv[64 * 16];
    __shared__ int   mink_s[64 * 16];
    __shared__ int   idx_sh[64];

    const int t  = threadIdx.x;
    const int tr = t & 15;
    const int tc = t >> 4;
    const int rbase = blockIdx.x * 64;

    // r = z - zp
    #pragma unroll
    for (int jj = 0; jj < 8; ++jj) {
        int f   = t + 256 * jj;       // 0..2047
        int row = f >> 5;             // 0..63
        int c4  = (f & 31) << 2;      // 0..124
        float4 zv = *(const float4*)(z  + (size_t)(rbase + row) * 128 + c4);
        float4 pv = *(const float4*)(zp + (size_t)(rbase + row) * 128 + c4);
        float4 rv = make_float4(zv.x - pv.x, zv.y - pv.y, zv.z - pv.z, zv.w - pv.w);
        *(float4*)&r_lds[row * 132 + c4] = rv;
    }
    __syncthreads();

    for (int q = 0; q < 8; ++q) {
        float mind[4];
        int   mink[4];
        #pragma unroll
        for (int i = 0; i < 4; ++i) { mind[i] = 3.4e38f; mink[i] = 0; }

        for (int cb0 = 0; cb0 < 1024; cb0 += 32) {
            // stage 32 codebook rows (1024 float4 / 256 threads)
            #pragma unroll
            for (int jj = 0; jj < 4; ++jj) {
                int f    = t + 256 * jj;       // 0..1023
                int crow = f >> 5;             // 0..31
                int c4   = (f & 31) << 2;
                float4 v = *(const float4*)(codebooks +
                           ((size_t)q * 1024 + cb0 + crow) * 128 + c4);
                *(float4*)&cbs[crow * 132 + c4] = v;
            }
            __syncthreads();

            float accd[4][2];
            #pragma unroll
            for (int i = 0; i < 4; ++i) { accd[i][0] = 0.f; accd[i][1] = 0.f; }

            #pragma unroll 4
            for (int d4 = 0; d4 < 32; ++d4) {
                float4 a0 = *(float4*)&r_lds[(tr +  0) * 132 + d4 * 4];
                float4 a1 = *(float4*)&r_lds[(tr + 16) * 132 + d4 * 4];
                float4 a2 = *(float4*)&r_lds[(tr + 32) * 132 + d4 * 4];
                float4 a3 = *(float4*)&r_lds[(tr + 48) * 132 + d4 * 4];
                float4 b0 = *(float4*)&cbs[(tc +  0) * 132 + d4 * 4];
                float4 b1 = *(float4*)&cbs[(tc + 16) * 132 + d4 * 4];
                #define DOT4(ACC, A, B) ACC += A.x*B.x + A.y*B.y + A.z*B.z + A.w*B.w
                DOT4(accd[0][0], a0, b0); DOT4(accd[0][1], a0, b1);
                DOT4(accd[1][0], a1, b0); DOT4(accd[1][1], a1, b1);
                DOT4(accd[2][0], a2, b0); DOT4(accd[2][1], a2, b1);
                DOT4(accd[3][0], a3, b0); DOT4(accd[3][1], a3, b1);
                #undef DOT4
            }
            __syncthreads();   // before next chunk overwrites cbs

            #pragma unroll
            for (int j = 0; j < 2; ++j) {
                int k  = cb0 + tc + 16 * j;
                float cn = cbn[q * 1024 + k];
                #pragma unroll
                for (int i = 0; i < 4; ++i) {
                    float d = cn - 2.f * accd[i][j];
                    if (d < mind[i]) { mind[i] = d; mink[i] = k; }
                }
            }
        }

        #pragma unroll
        for (int i = 0; i < 4; ++i) {
            int row = tr + 16 * i;
            minv[row * 16 + tc]   = mind[i];
            mink_s[row * 16 + tc] = mink[i];
        }
        __syncthreads();
        if (t < 64) {
            float best = minv[t * 16];
            int   bi   = mink_s[t * 16];
            for (int c = 1; c < 16; ++c) {
                float v  = minv[t * 16 + c];
                int   k2 = mink_s[t * 16 + c];
                if (v < best || (v == best && k2 < bi)) { best = v; bi = k2; }
            }
            idx_sh[t] = bi;
        }
        __syncthreads();

        // r -= cb[idx]
        #pragma unroll
        for (int jj = 0; jj < 8; ++jj) {
            int f   = t + 256 * jj;
            int row = f >> 5;
            int c4  = (f & 31) << 2;
            int k   = idx_sh[row];
            float4 v = *(const float4*)(codebooks + ((size_t)q * 1024 + k) * 128 + c4);
            float4* rp = (float4*)&r_lds[row * 132 + c4];
            float4 rv = *rp;
            rv.x -= v.x; rv.y -= v.y; rv.z -= v.z; rv.w -= v.w;
            *rp = rv;
        }
        __syncthreads();
    }

    // zhat = z - r_final (each element read once then written; alias-safe)
    #pragma unroll
    for (int jj = 0; jj < 8; ++jj) {
        int f   = t + 256 * jj;
        int row = f >> 5;
        int c4  = (f & 31) << 2;
        float4 zv = *(const float4*)(z + (size_t)(rbase + row) * 128 + c4);
        float4 rv = *(float4*)&r_lds[row * 132 + c4];
        float4 o = make_float4(zv.x - rv.x, zv.y - rv.y, zv.z - rv.z, zv.w - rv.w);
        *(float4*)(zhat + (size_t)(rbase + row) * 128 + c4) = o;
    }
}

// ---------------------------------------------------------------------------
extern "C" void kernel_launch(void* const* d_in, const int* in_sizes, int n_in,
                              void* d_out, int out_size, void* d_ws, size_t ws_size,
                              hipStream_t stream)
{
    const float* s    = (const float*)d_in[0];
    const float* goal = (const float*)d_in[1];
    const float* pW0  = (const float*)d_in[2];  const float* pb0 = (const float*)d_in[3];
    const float* pW1  = (const float*)d_in[4];  const float* pb1 = (const float*)d_in[5];
    const float* pW2  = (const float*)d_in[6];  const float* pb2 = (const float*)d_in[7];
    const float* qW0  = (const float*)d_in[8];  const float* qb0 = (const float*)d_in[9];
    const float* qW1  = (const float*)d_in[10]; const float* qb1 = (const float*)d_in[11];
    const float* qW2  = (const float*)d_in[12]; const float* qb2 = (const float*)d_in[13];
    const float* dW0  = (const float*)d_in[14]; const float* db0 = (const float*)d_in[15];
    const float* dW1  = (const float*)d_in[16]; const float* db1 = (const float*)d_in[17];
    const float* dW2  = (const float*)d_in[18]; const float* db2 = (const float*)d_in[19];
    const float* cb   = (const float*)d_in[20];
    float* out = (float*)d_out;

    // ---- workspace layout (adaptive to ws_size; deterministic per process) ----
    float* ws   = (float*)d_ws;
    float* zp   = ws;                                  // [N,128]
    float* zbuf = zp + (size_t)NROWS * 128;            // [N,128]; zhat in-place
    float* cbn  = zbuf + (size_t)NROWS * 128;          // [8192]
    float* bufA = cbn + 8192;                          // [CH,1024]
    // bufB follows bufA

    size_t used_elems  = (size_t)NROWS * 128 * 2 + 8192;
    size_t total_elems = ws_size / sizeof(float);
    size_t avail       = (total_elems > used_elems) ? (total_elems - used_elems) : 0;
    size_t ch          = avail / 2048;                 // two CH*1024 buffers
    if (ch > NROWS) ch = NROWS;
    ch &= ~(size_t)63;                                 // multiple of 64
    if (ch < 64) ch = 64;                              // last-resort (needs 512KB ws)
    const int CH = (int)ch;
    float* bufB = bufA + (size_t)CH * 1024;

    dim3 blk(256);

    cbnorm_kernel<<<32, blk, 0, stream>>>(cb, cbn);

    // prior + posterior, chunked over rows
    for (int off = 0; off < NROWS; off += CH) {
        int rows = (NROWS - off) < CH ? (NROWS - off) : CH;
        dim3 gy(8, rows / 64);
        const float* sC = s + (size_t)off * 256;
        const float* gC = goal + (size_t)off * 128;
        // prior: s -> 512 -> 512 -> zp
        gemm_f32<<<gy, blk, 0, stream>>>(sC, 256, nullptr, 0, pW0, pb0, bufA, 256, 512, 1);
        gemm_f32<<<gy, blk, 0, stream>>>(bufA, 512, nullptr, 0, pW1, pb1, bufB, 512, 512, 1);
        gemm_f32<<<dim3(2, rows / 64), blk, 0, stream>>>(bufB, 512, nullptr, 0, pW2, pb2,
                                                         zp + (size_t)off * 128, 512, 128, 0);
        // posterior: [s,goal] -> 512 -> 512 -> z
        gemm_f32<<<gy, blk, 0, stream>>>(sC, 256, gC, 128, qW0, qb0, bufA, 384, 512, 1);
        gemm_f32<<<gy, blk, 0, stream>>>(bufA, 512, nullptr, 0, qW1, qb1, bufB, 512, 512, 1);
        gemm_f32<<<dim3(2, rows / 64), blk, 0, stream>>>(bufB, 512, nullptr, 0, qW2, qb2,
                                                         zbuf + (size_t)off * 128, 512, 128, 0);
    }

    // residual VQ (full N): zbuf <- zhat (in place)
    rvq_kernel<<<NROWS / 64, blk, 0, stream>>>(zbuf, zp, cb, cbn, zbuf);

    // decoder, chunked
    for (int off = 0; off < NROWS; off += CH) {
        int rows = (NROWS - off) < CH ? (NROWS - off) : CH;
        const float* sC = s + (size_t)off * 256;
        const float* zC = zbuf + (size_t)off * 128;
        gemm_f32<<<dim3(16, rows / 64), blk, 0, stream>>>(sC, 256, zC, 128, dW0, db0, bufA, 384, 1024, 1);
        gemm_f32<<<dim3(16, rows / 64), blk, 0, stream>>>(bufA, 1024, nullptr, 0, dW1, db1, bufB, 1024, 1024, 1);
        gemm_f32<<<dim3(1, rows / 64),  blk, 0, stream>>>(bufB, 1024, nullptr, 0, dW2, db2,
                                                          out + (size_t)off * 32, 1024, 32, 0);
    }
}

// Round 3
// 4208.418 us; speedup vs baseline: 1.7537x; 1.7537x over previous
//
#include <hip/hip_runtime.h>

#define NROWS 65536
typedef unsigned short u16;
typedef __attribute__((ext_vector_type(8))) short bf16x8;
typedef __attribute__((ext_vector_type(4))) float f32x4;

__device__ __forceinline__ u16 tobf(float v) {
    unsigned b = __float_as_uint(v);
    b += 0x7fffu + ((b >> 16) & 1u);          // RNE
    return (u16)(b >> 16);
}
__device__ __forceinline__ float frombf(u16 h) {
    return __uint_as_float(((unsigned)h) << 16);
}
__device__ __forceinline__ void split2(float v, u16& h, u16& l) {
    h = tobf(v);
    l = tobf(v - frombf(h));
}

// ---------------------------------------------------------------------------
// Weight prep: W[K][N] fp32 -> Wth[N][K], Wtl[N][K] bf16 (transposed + split).
// Tile 64k x 32n per block. grid = (N/32, K/64), 256 threads.
// ---------------------------------------------------------------------------
__global__ __launch_bounds__(256)
void wsplit(const float* __restrict__ W, u16* __restrict__ Th, u16* __restrict__ Tl,
            int K, int N)
{
    __shared__ float Tt[32][65];
    const int t = threadIdx.x;
    const int nb = blockIdx.x * 32, kb = blockIdx.y * 64;
    #pragma unroll
    for (int j = 0; j < 2; ++j) {
        int fi = j * 256 + t;            // 0..511 float4s (64k x 32n)
        int kk = fi >> 3;                // 0..63
        int n4 = (fi & 7) * 4;           // 0..28
        float4 v = *(const float4*)&W[(size_t)(kb + kk) * N + nb + n4];
        Tt[n4 + 0][kk] = v.x; Tt[n4 + 1][kk] = v.y;
        Tt[n4 + 2][kk] = v.z; Tt[n4 + 3][kk] = v.w;
    }
    __syncthreads();
    #pragma unroll
    for (int j = 0; j < 2; ++j) {
        int oi = j * 256 + t;            // 0..511 ushort4s (32n x 16)
        int n  = oi >> 4;                // 0..31
        int k4 = (oi & 15) * 4;          // 0..60
        ushort4 h, l;
        split2(Tt[n][k4 + 0], h.x, l.x); split2(Tt[n][k4 + 1], h.y, l.y);
        split2(Tt[n][k4 + 2], h.z, l.z); split2(Tt[n][k4 + 3], h.w, l.w);
        size_t oa = (size_t)(nb + n) * K + kb + k4;
        *(ushort4*)(Th + oa) = h;
        *(ushort4*)(Tl + oa) = l;
    }
}

// ---------------------------------------------------------------------------
// bf16x3-split MFMA GEMM: C = act( concat(A1,A2)[M,Kin] @ W + b ), fp32 I/O.
// C = Ahi@Whi + Ahi@Wlo + Alo@Whi  (error ~2^-18 rel — fp32-equivalent).
// 256 thr = 4 waves at (NWY x NWX); wave tile = FM*16 x FN*16; BK = 32.
// ---------------------------------------------------------------------------
template<int FM, int FN, int NWX, int NWY, int RELU>
__global__ __launch_bounds__(256)
void gemm3(const float* __restrict__ A1, int w1,
           const float* __restrict__ A2, int w2,
           const u16* __restrict__ Wth, const u16* __restrict__ Wtl,
           const float* __restrict__ bias,
           float* __restrict__ C, int Kin, int Nout)
{
    constexpr int BM = NWY * FM * 16;
    constexpr int BN = NWX * FN * 16;
    static_assert(NWX * NWY == 4, "4 waves");
    __shared__ u16 Ah[BM * 32], Al[BM * 32], Bh[BN * 32], Bl[BN * 32];

    const int t = threadIdx.x, lane = t & 63, w = t >> 6;
    const int wx = w % NWX, wy = w / NWX;
    const int lg = lane >> 4, lm = lane & 15;
    const int rbase = blockIdx.y * BM, cbase = blockIdx.x * BN;

    f32x4 acc[FM][FN];
    #pragma unroll
    for (int i = 0; i < FM; ++i)
        #pragma unroll
        for (int j = 0; j < FN; ++j) acc[i][j] = (f32x4){0.f, 0.f, 0.f, 0.f};

    for (int kb = 0; kb < Kin; kb += 32) {
        // ---- stage A (fp32 load, split to hi/lo bf16), layout [m][k], 64B rows
        #pragma unroll
        for (int j = 0; j < BM / 32; ++j) {
            int fi  = j * 256 + t;
            int row = fi >> 3;
            int k   = (fi & 7) * 4;
            int gc  = kb + k;
            const float* src = (gc < w1) ? (A1 + (size_t)(rbase + row) * w1 + gc)
                                         : (A2 + (size_t)(rbase + row) * w2 + (gc - w1));
            float4 v = *(const float4*)src;
            ushort4 h, l;
            split2(v.x, h.x, l.x); split2(v.y, h.y, l.y);
            split2(v.z, h.z, l.z); split2(v.w, h.w, l.w);
            *(ushort4*)&Ah[row * 32 + k] = h;
            *(ushort4*)&Al[row * 32 + k] = l;
        }
        // ---- stage B (pre-split bf16 [n][k])
        #pragma unroll
        for (int j = 0; j < BN / 32; ++j) {
            int fi   = j * 256 + t;
            int nrow = fi >> 3;
            int k    = (fi & 7) * 4;
            size_t ga = (size_t)(cbase + nrow) * Kin + kb + k;
            *(ushort4*)&Bh[nrow * 32 + k] = *(const ushort4*)(Wth + ga);
            *(ushort4*)&Bl[nrow * 32 + k] = *(const ushort4*)(Wtl + ga);
        }
        __syncthreads();

        bf16x8 a_h[FM], a_l[FM], b_h[FN], b_l[FN];
        #pragma unroll
        for (int fm = 0; fm < FM; ++fm) {
            int off = (wy * FM * 16 + fm * 16 + lm) * 32 + lg * 8;
            a_h[fm] = *(const bf16x8*)&Ah[off];
            a_l[fm] = *(const bf16x8*)&Al[off];
        }
        #pragma unroll
        for (int fn = 0; fn < FN; ++fn) {
            int off = (wx * FN * 16 + fn * 16 + lm) * 32 + lg * 8;
            b_h[fn] = *(const bf16x8*)&Bh[off];
            b_l[fn] = *(const bf16x8*)&Bl[off];
        }
        #pragma unroll
        for (int fm = 0; fm < FM; ++fm)
            #pragma unroll
            for (int fn = 0; fn < FN; ++fn) {
                acc[fm][fn] = __builtin_amdgcn_mfma_f32_16x16x32_bf16(a_h[fm], b_h[fn], acc[fm][fn], 0, 0, 0);
                acc[fm][fn] = __builtin_amdgcn_mfma_f32_16x16x32_bf16(a_h[fm], b_l[fn], acc[fm][fn], 0, 0, 0);
                acc[fm][fn] = __builtin_amdgcn_mfma_f32_16x16x32_bf16(a_l[fm], b_h[fn], acc[fm][fn], 0, 0, 0);
            }
        __syncthreads();
    }

    float bn_[FN];
    #pragma unroll
    for (int fn = 0; fn < FN; ++fn)
        bn_[fn] = bias[cbase + wx * FN * 16 + fn * 16 + lm];
    #pragma unroll
    for (int fm = 0; fm < FM; ++fm)
        #pragma unroll
        for (int fn = 0; fn < FN; ++fn)
            #pragma unroll
            for (int r = 0; r < 4; ++r) {
                int m = rbase + wy * FM * 16 + fm * 16 + lg * 4 + r;
                int n = cbase + wx * FN * 16 + fn * 16 + lm;
                float v = acc[fm][fn][r] + bn_[fn];
                if (RELU) v = fmaxf(v, 0.f);
                C[(size_t)m * Nout + n] = v;
            }
}

// ---------------------------------------------------------------------------
__global__ __launch_bounds__(256)
void cbnorm_kernel(const float* __restrict__ cb, float* __restrict__ cbn)
{
    int code = blockIdx.x * 256 + threadIdx.x;      // 0..8191
    const float* p = cb + (size_t)code * 128;
    float s = 0.f;
    #pragma unroll 8
    for (int d4 = 0; d4 < 32; ++d4) {
        float4 v = *(const float4*)(p + d4 * 4);
        s += v.x * v.x + v.y * v.y + v.z * v.z + v.w * v.w;
    }
    cbn[code] = s;
}

// ---------------------------------------------------------------------------
// Fused residual VQ (fp32). 64 rows/block; 64-code chunks: 8 ds_read_b128
// per 64 FMA (VALU-bound). LDS 75.5 KB -> 2 blocks/CU on gfx950 (160 KB).
// ---------------------------------------------------------------------------
__global__ __launch_bounds__(256)
void rvq_kernel(float* __restrict__ z, const float* __restrict__ zp,
                const float* __restrict__ codebooks, const float* __restrict__ cbn,
                float* __restrict__ zhat /* aliases z */)
{
    __shared__ float r_lds[64 * 132];
    __shared__ float cbs[64 * 132];
    __shared__ float minv[64 * 16];
    __shared__ int   mink_s[64 * 16];
    __shared__ int   idx_sh[64];

    const int t  = threadIdx.x;
    const int tr = t & 15;
    const int tc = t >> 4;
    const int rbase = blockIdx.x * 64;

    #pragma unroll
    for (int jj = 0; jj < 8; ++jj) {
        int f   = t + 256 * jj;
        int row = f >> 5;
        int c4  = (f & 31) << 2;
        float4 zv = *(const float4*)(z  + (size_t)(rbase + row) * 128 + c4);
        float4 pv = *(const float4*)(zp + (size_t)(rbase + row) * 128 + c4);
        float4 rv = make_float4(zv.x - pv.x, zv.y - pv.y, zv.z - pv.z, zv.w - pv.w);
        *(float4*)&r_lds[row * 132 + c4] = rv;
    }
    __syncthreads();

    for (int q = 0; q < 8; ++q) {
        float mind[4];
        int   mink[4];
        #pragma unroll
        for (int i = 0; i < 4; ++i) { mind[i] = 3.4e38f; mink[i] = 0; }

        for (int cb0 = 0; cb0 < 1024; cb0 += 64) {
            #pragma unroll
            for (int jj = 0; jj < 8; ++jj) {
                int f    = t + 256 * jj;
                int crow = f >> 5;
                int c4   = (f & 31) << 2;
                float4 v = *(const float4*)(codebooks +
                           ((size_t)q * 1024 + cb0 + crow) * 128 + c4);
                *(float4*)&cbs[crow * 132 + c4] = v;
            }
            __syncthreads();

            float accd[4][4];
            #pragma unroll
            for (int i = 0; i < 4; ++i)
                #pragma unroll
                for (int j = 0; j < 4; ++j) accd[i][j] = 0.f;

            #pragma unroll 4
            for (int d4 = 0; d4 < 32; ++d4) {
                float4 a0 = *(float4*)&r_lds[(tr +  0) * 132 + d4 * 4];
                float4 a1 = *(float4*)&r_lds[(tr + 16) * 132 + d4 * 4];
                float4 a2 = *(float4*)&r_lds[(tr + 32) * 132 + d4 * 4];
                float4 a3 = *(float4*)&r_lds[(tr + 48) * 132 + d4 * 4];
                float4 b0 = *(float4*)&cbs[(tc +  0) * 132 + d4 * 4];
                float4 b1 = *(float4*)&cbs[(tc + 16) * 132 + d4 * 4];
                float4 b2 = *(float4*)&cbs[(tc + 32) * 132 + d4 * 4];
                float4 b3 = *(float4*)&cbs[(tc + 48) * 132 + d4 * 4];
                #define DOT4(ACC, A, B) ACC += A.x*B.x + A.y*B.y + A.z*B.z + A.w*B.w
                DOT4(accd[0][0], a0, b0); DOT4(accd[0][1], a0, b1); DOT4(accd[0][2], a0, b2); DOT4(accd[0][3], a0, b3);
                DOT4(accd[1][0], a1, b0); DOT4(accd[1][1], a1, b1); DOT4(accd[1][2], a1, b2); DOT4(accd[1][3], a1, b3);
                DOT4(accd[2][0], a2, b0); DOT4(accd[2][1], a2, b1); DOT4(accd[2][2], a2, b2); DOT4(accd[2][3], a2, b3);
                DOT4(accd[3][0], a3, b0); DOT4(accd[3][1], a3, b1); DOT4(accd[3][2], a3, b2); DOT4(accd[3][3], a3, b3);
                #undef DOT4
            }
            __syncthreads();

            #pragma unroll
            for (int j = 0; j < 4; ++j) {
                int k  = cb0 + tc + 16 * j;
                float cn = cbn[q * 1024 + k];
                #pragma unroll
                for (int i = 0; i < 4; ++i) {
                    float d = cn - 2.f * accd[i][j];
                    if (d < mind[i]) { mind[i] = d; mink[i] = k; }
                }
            }
        }

        #pragma unroll
        for (int i = 0; i < 4; ++i) {
            int row = tr + 16 * i;
            minv[row * 16 + tc]   = mind[i];
            mink_s[row * 16 + tc] = mink[i];
        }
        __syncthreads();
        if (t < 64) {
            float best = minv[t * 16];
            int   bi   = mink_s[t * 16];
            for (int c = 1; c < 16; ++c) {
                float v  = minv[t * 16 + c];
                int   k2 = mink_s[t * 16 + c];
                if (v < best || (v == best && k2 < bi)) { best = v; bi = k2; }
            }
            idx_sh[t] = bi;
        }
        __syncthreads();

        #pragma unroll
        for (int jj = 0; jj < 8; ++jj) {
            int f   = t + 256 * jj;
            int row = f >> 5;
            int c4  = (f & 31) << 2;
            int k   = idx_sh[row];
            float4 v = *(const float4*)(codebooks + ((size_t)q * 1024 + k) * 128 + c4);
            float4* rp = (float4*)&r_lds[row * 132 + c4];
            float4 rv = *rp;
            rv.x -= v.x; rv.y -= v.y; rv.z -= v.z; rv.w -= v.w;
            *rp = rv;
        }
        __syncthreads();
    }

    #pragma unroll
    for (int jj = 0; jj < 8; ++jj) {
        int f   = t + 256 * jj;
        int row = f >> 5;
        int c4  = (f & 31) << 2;
        float4 zv = *(const float4*)(z + (size_t)(rbase + row) * 128 + c4);
        float4 rv = *(float4*)&r_lds[row * 132 + c4];
        float4 o = make_float4(zv.x - rv.x, zv.y - rv.y, zv.z - rv.z, zv.w - rv.w);
        *(float4*)(zhat + (size_t)(rbase + row) * 128 + c4) = o;
    }
}

// ---------------------------------------------------------------------------
extern "C" void kernel_launch(void* const* d_in, const int* in_sizes, int n_in,
                              void* d_out, int out_size, void* d_ws, size_t ws_size,
                              hipStream_t stream)
{
    const float* s    = (const float*)d_in[0];
    const float* goal = (const float*)d_in[1];
    const float* Wp[9]  = { (const float*)d_in[2],  (const float*)d_in[4],  (const float*)d_in[6],
                            (const float*)d_in[8],  (const float*)d_in[10], (const float*)d_in[12],
                            (const float*)d_in[14], (const float*)d_in[16], (const float*)d_in[18] };
    const float* Bp[9]  = { (const float*)d_in[3],  (const float*)d_in[5],  (const float*)d_in[7],
                            (const float*)d_in[9],  (const float*)d_in[11], (const float*)d_in[13],
                            (const float*)d_in[15], (const float*)d_in[17], (const float*)d_in[19] };
    const float* cb   = (const float*)d_in[20];
    float* out = (float*)d_out;

    static const int WK[9] = { 256, 512, 512, 384, 512, 512, 384, 1024, 1024 };
    static const int WN[9] = { 512, 512, 128, 512, 512, 128, 1024, 1024, 32 };
    size_t woff[10]; woff[0] = 0;
    for (int i = 0; i < 9; ++i) woff[i + 1] = woff[i] + (size_t)WK[i] * WN[i]; // total 2457600

    float* zp  = (float*)d_ws;                       // [N,128]
    float* zz  = zp + (size_t)NROWS * 128;           // [N,128]; zhat in-place
    float* cbn = zz + (size_t)NROWS * 128;           // [8192]
    u16*  Wth  = (u16*)(cbn + 8192);
    u16*  Wtl  = Wth + woff[9];
    uintptr_t bA = ((uintptr_t)(Wtl + woff[9]) + 255) & ~(uintptr_t)255;
    float* bufA = (float*)bA;

    size_t used = (size_t)(bA - (uintptr_t)d_ws);
    size_t avail = (ws_size > used) ? (ws_size - used) : 0;
    size_t ch = avail / (2 * 1024 * sizeof(float));
    if (ch > NROWS) ch = NROWS;
    ch &= ~(size_t)127;
    if (ch < 128) ch = 128;
    const int CH = (int)ch;
    float* bufB = bufA + (size_t)CH * 1024;

    dim3 blk(256);

    cbnorm_kernel<<<32, blk, 0, stream>>>(cb, cbn);
    for (int i = 0; i < 9; ++i)
        wsplit<<<dim3(WN[i] / 32, WK[i] / 64), blk, 0, stream>>>(Wp[i], Wth + woff[i], Wtl + woff[i], WK[i], WN[i]);

    // prior + posterior, chunked
    for (int off = 0; off < NROWS; off += CH) {
        int rows = (NROWS - off) < CH ? (NROWS - off) : CH;
        int gy = rows / 128;
        const float* sC = s + (size_t)off * 256;
        const float* gC = goal + (size_t)off * 128;
        gemm3<4,4,2,2,1><<<dim3(4, gy), blk, 0, stream>>>(sC, 256, nullptr, 0, Wth + woff[0], Wtl + woff[0], Bp[0], bufA, 256, 512);
        gemm3<4,4,2,2,1><<<dim3(4, gy), blk, 0, stream>>>(bufA, 512, nullptr, 0, Wth + woff[1], Wtl + woff[1], Bp[1], bufB, 512, 512);
        gemm3<4,4,2,2,0><<<dim3(1, gy), blk, 0, stream>>>(bufB, 512, nullptr, 0, Wth + woff[2], Wtl + woff[2], Bp[2], zp + (size_t)off * 128, 512, 128);
        gemm3<4,4,2,2,1><<<dim3(4, gy), blk, 0, stream>>>(sC, 256, gC, 128, Wth + woff[3], Wtl + woff[3], Bp[3], bufA, 384, 512);
        gemm3<4,4,2,2,1><<<dim3(4, gy), blk, 0, stream>>>(bufA, 512, nullptr, 0, Wth + woff[4], Wtl + woff[4], Bp[4], bufB, 512, 512);
        gemm3<4,4,2,2,0><<<dim3(1, gy), blk, 0, stream>>>(bufB, 512, nullptr, 0, Wth + woff[5], Wtl + woff[5], Bp[5], zz + (size_t)off * 128, 512, 128);
    }

    rvq_kernel<<<NROWS / 64, blk, 0, stream>>>(zz, zp, cb, cbn, zz);

    // decoder, chunked
    for (int off = 0; off < NROWS; off += CH) {
        int rows = (NROWS - off) < CH ? (NROWS - off) : CH;
        int gy = rows / 128;
        const float* sC = s + (size_t)off * 256;
        const float* zC = zz + (size_t)off * 128;
        gemm3<4,4,2,2,1><<<dim3(8, gy), blk, 0, stream>>>(sC, 256, zC, 128, Wth + woff[6], Wtl + woff[6], Bp[6], bufA, 384, 1024);
        gemm3<4,4,2,2,1><<<dim3(8, gy), blk, 0, stream>>>(bufA, 1024, nullptr, 0, Wth + woff[7], Wtl + woff[7], Bp[7], bufB, 1024, 1024);
        gemm3<2,2,1,4,0><<<dim3(1, gy), blk, 0, stream>>>(bufB, 1024, nullptr, 0, Wth + woff[8], Wtl + woff[8], Bp[8], out + (size_t)off * 32, 1024, 32);
    }
}

// Round 4
// 2791.694 us; speedup vs baseline: 2.6437x; 1.5075x over previous
//
#include <hip/hip_runtime.h>

#define NROWS 65536
typedef unsigned short u16;
typedef __attribute__((ext_vector_type(8))) short bf16x8;
typedef __attribute__((ext_vector_type(4))) float f32x4;

__device__ __forceinline__ u16 tobf(float v) {
    unsigned b = __float_as_uint(v);
    b += 0x7fffu + ((b >> 16) & 1u);          // RNE
    return (u16)(b >> 16);
}
__device__ __forceinline__ float frombf(u16 h) {
    return __uint_as_float(((unsigned)h) << 16);
}
__device__ __forceinline__ void split2(float v, u16& h, u16& l) {
    h = tobf(v);
    l = tobf(v - frombf(h));
}

// ---------------------------------------------------------------------------
// Weight prep: W[K][N] fp32 -> Wth[N][K], Wtl[N][K] bf16 (transposed + split).
// ---------------------------------------------------------------------------
__global__ __launch_bounds__(256)
void wsplit(const float* __restrict__ W, u16* __restrict__ Th, u16* __restrict__ Tl,
            int K, int N)
{
    __shared__ float Tt[32][65];
    const int t = threadIdx.x;
    const int nb = blockIdx.x * 32, kb = blockIdx.y * 64;
    #pragma unroll
    for (int j = 0; j < 2; ++j) {
        int fi = j * 256 + t;
        int kk = fi >> 3;
        int n4 = (fi & 7) * 4;
        float4 v = *(const float4*)&W[(size_t)(kb + kk) * N + nb + n4];
        Tt[n4 + 0][kk] = v.x; Tt[n4 + 1][kk] = v.y;
        Tt[n4 + 2][kk] = v.z; Tt[n4 + 3][kk] = v.w;
    }
    __syncthreads();
    #pragma unroll
    for (int j = 0; j < 2; ++j) {
        int oi = j * 256 + t;
        int n  = oi >> 4;
        int k4 = (oi & 15) * 4;
        ushort4 h, l;
        split2(Tt[n][k4 + 0], h.x, l.x); split2(Tt[n][k4 + 1], h.y, l.y);
        split2(Tt[n][k4 + 2], h.z, l.z); split2(Tt[n][k4 + 3], h.w, l.w);
        size_t oa = (size_t)(nb + n) * K + kb + k4;
        *(ushort4*)(Th + oa) = h;
        *(ushort4*)(Tl + oa) = l;
    }
}

// ---------------------------------------------------------------------------
// bf16x3-split MFMA GEMM. LDS tile stride padded to 40 u16 (80 B) so frag
// ds_read_b128 are 2-way-bank-aliased (free) instead of 8-way at stride 32.
// ---------------------------------------------------------------------------
template<int FM, int FN, int NWX, int NWY, int RELU>
__global__ __launch_bounds__(256)
void gemm3(const float* __restrict__ A1, int w1,
           const float* __restrict__ A2, int w2,
           const u16* __restrict__ Wth, const u16* __restrict__ Wtl,
           const float* __restrict__ bias,
           float* __restrict__ C, int Kin, int Nout)
{
    constexpr int BM = NWY * FM * 16;
    constexpr int BN = NWX * FN * 16;
    constexpr int LDT = 40;                   // padded (u16) stride
    static_assert(NWX * NWY == 4, "4 waves");
    __shared__ u16 Ah[BM * LDT], Al[BM * LDT], Bh[BN * LDT], Bl[BN * LDT];

    const int t = threadIdx.x, lane = t & 63, w = t >> 6;
    const int wx = w % NWX, wy = w / NWX;
    const int lg = lane >> 4, lm = lane & 15;
    const int rbase = blockIdx.y * BM, cbase = blockIdx.x * BN;

    f32x4 acc[FM][FN];
    #pragma unroll
    for (int i = 0; i < FM; ++i)
        #pragma unroll
        for (int j = 0; j < FN; ++j) acc[i][j] = (f32x4){0.f, 0.f, 0.f, 0.f};

    for (int kb = 0; kb < Kin; kb += 32) {
        #pragma unroll
        for (int j = 0; j < BM / 32; ++j) {
            int fi  = j * 256 + t;
            int row = fi >> 3;
            int k   = (fi & 7) * 4;
            int gc  = kb + k;
            const float* src = (gc < w1) ? (A1 + (size_t)(rbase + row) * w1 + gc)
                                         : (A2 + (size_t)(rbase + row) * w2 + (gc - w1));
            float4 v = *(const float4*)src;
            ushort4 h, l;
            split2(v.x, h.x, l.x); split2(v.y, h.y, l.y);
            split2(v.z, h.z, l.z); split2(v.w, h.w, l.w);
            *(ushort4*)&Ah[row * LDT + k] = h;
            *(ushort4*)&Al[row * LDT + k] = l;
        }
        #pragma unroll
        for (int j = 0; j < BN / 32; ++j) {
            int fi   = j * 256 + t;
            int nrow = fi >> 3;
            int k    = (fi & 7) * 4;
            size_t ga = (size_t)(cbase + nrow) * Kin + kb + k;
            *(ushort4*)&Bh[nrow * LDT + k] = *(const ushort4*)(Wth + ga);
            *(ushort4*)&Bl[nrow * LDT + k] = *(const ushort4*)(Wtl + ga);
        }
        __syncthreads();

        bf16x8 a_h[FM], a_l[FM], b_h[FN], b_l[FN];
        #pragma unroll
        for (int fm = 0; fm < FM; ++fm) {
            int off = (wy * FM * 16 + fm * 16 + lm) * LDT + lg * 8;
            a_h[fm] = *(const bf16x8*)&Ah[off];
            a_l[fm] = *(const bf16x8*)&Al[off];
        }
        #pragma unroll
        for (int fn = 0; fn < FN; ++fn) {
            int off = (wx * FN * 16 + fn * 16 + lm) * LDT + lg * 8;
            b_h[fn] = *(const bf16x8*)&Bh[off];
            b_l[fn] = *(const bf16x8*)&Bl[off];
        }
        #pragma unroll
        for (int fm = 0; fm < FM; ++fm)
            #pragma unroll
            for (int fn = 0; fn < FN; ++fn) {
                acc[fm][fn] = __builtin_amdgcn_mfma_f32_16x16x32_bf16(a_h[fm], b_h[fn], acc[fm][fn], 0, 0, 0);
                acc[fm][fn] = __builtin_amdgcn_mfma_f32_16x16x32_bf16(a_h[fm], b_l[fn], acc[fm][fn], 0, 0, 0);
                acc[fm][fn] = __builtin_amdgcn_mfma_f32_16x16x32_bf16(a_l[fm], b_h[fn], acc[fm][fn], 0, 0, 0);
            }
        __syncthreads();
    }

    float bn_[FN];
    #pragma unroll
    for (int fn = 0; fn < FN; ++fn)
        bn_[fn] = bias[cbase + wx * FN * 16 + fn * 16 + lm];
    #pragma unroll
    for (int fm = 0; fm < FM; ++fm)
        #pragma unroll
        for (int fn = 0; fn < FN; ++fn)
            #pragma unroll
            for (int r = 0; r < 4; ++r) {
                int m = rbase + wy * FM * 16 + fm * 16 + lg * 4 + r;
                int n = cbase + wx * FN * 16 + fn * 16 + lm;
                float v = acc[fm][fn][r] + bn_[fn];
                if (RELU) v = fmaxf(v, 0.f);
                C[(size_t)m * Nout + n] = v;
            }
}

// ---------------------------------------------------------------------------
__global__ __launch_bounds__(256)
void cbnorm_kernel(const float* __restrict__ cb, float* __restrict__ cbn)
{
    int code = blockIdx.x * 256 + threadIdx.x;      // 0..8191
    const float* p = cb + (size_t)code * 128;
    float s = 0.f;
    #pragma unroll 8
    for (int d4 = 0; d4 < 32; ++d4) {
        float4 v = *(const float4*)(p + d4 * 4);
        s += v.x * v.x + v.y * v.y + v.z * v.z + v.w * v.w;
    }
    cbn[code] = s;
}

// ---------------------------------------------------------------------------
// Codebook split: cb fp32 [8*1024*128] -> CBh, CBl bf16 (same layout).
// ---------------------------------------------------------------------------
__global__ __launch_bounds__(256)
void cbsplit(const float* __restrict__ cb, u16* __restrict__ CBh, u16* __restrict__ CBl)
{
    int i = (blockIdx.x * 256 + threadIdx.x) * 4;   // 1048576 elems / 4
    float4 v = *(const float4*)(cb + i);
    ushort4 h, l;
    split2(v.x, h.x, l.x); split2(v.y, h.y, l.y);
    split2(v.z, h.z, l.z); split2(v.w, h.w, l.w);
    *(ushort4*)(CBh + i) = h;
    *(ushort4*)(CBl + i) = l;
}

// ---------------------------------------------------------------------------
// MFMA residual VQ. 64 rows/block. Distance GEMM computed TRANSPOSED:
// S^T[code][row] = CB @ R^T, so C-layout puts one output row per lane
// (n = lane&15) and the argmin fold is lane-local over codes.
// 3-split bf16 MFMA (noise ~3e-5); top-2 tracked per row; if gap <= EPS the
// two candidates are recomputed exactly in fp32 -> argmin fp32-identical.
// CB hi/lo frags read directly from global (L2-resident, no LDS staging).
// ---------------------------------------------------------------------------
#define RVQ_EPS 4e-3f

__device__ __forceinline__ float dot128(const float* __restrict__ r,
                                        const float* __restrict__ c)
{
    float s = 0.f;
    #pragma unroll 8
    for (int i = 0; i < 32; ++i) {
        float4 a = *(const float4*)(r + i * 4);
        float4 b = *(const float4*)(c + i * 4);
        s += a.x * b.x + a.y * b.y + a.z * b.z + a.w * b.w;
    }
    return s;
}

__global__ __launch_bounds__(256, 2)
void rvq_mfma(float* __restrict__ z, const float* __restrict__ zp,
              const float* __restrict__ cbf,
              const u16* __restrict__ CBh, const u16* __restrict__ CBl,
              const float* __restrict__ cbn,
              float* __restrict__ zhat /* aliases z */)
{
    __shared__ float r_lds[64 * 132];
    __shared__ float cbn_lds[1024];
    __shared__ float red_m1[256];   // [w][nt][lm]
    __shared__ int   red_k1[256];
    __shared__ float red_m2[256];
    __shared__ int   red_k2[256];
    __shared__ int   idx_sh[64];

    const int t = threadIdx.x, lane = t & 63, w = t >> 6;
    const int lm = lane & 15, lg = lane >> 4;
    const int rbase = blockIdx.x * 64;

    // r = z - zp
    #pragma unroll
    for (int jj = 0; jj < 8; ++jj) {
        int f   = t + 256 * jj;
        int row = f >> 5;
        int c4  = (f & 31) << 2;
        float4 zv = *(const float4*)(z  + (size_t)(rbase + row) * 128 + c4);
        float4 pv = *(const float4*)(zp + (size_t)(rbase + row) * 128 + c4);
        float4 rv = make_float4(zv.x - pv.x, zv.y - pv.y, zv.z - pv.z, zv.w - pv.w);
        *(float4*)&r_lds[row * 132 + c4] = rv;
    }
    __syncthreads();

    for (int q = 0; q < 8; ++q) {
        // stage this quantizer's cbn; load R-frags (r_lds is stable here)
        {
            float4 v = *(const float4*)&cbn[q * 1024 + t * 4];
            *(float4*)&cbn_lds[t * 4] = v;
        }
        bf16x8 rh[4][4], rl[4][4];
        #pragma unroll
        for (int nt = 0; nt < 4; ++nt)
            #pragma unroll
            for (int ks = 0; ks < 4; ++ks) {
                const float* rp = &r_lds[(nt * 16 + lm) * 132 + ks * 32 + lg * 8];
                float4 v0 = *(const float4*)rp;
                float4 v1 = *(const float4*)(rp + 4);
                float fv[8] = { v0.x, v0.y, v0.z, v0.w, v1.x, v1.y, v1.z, v1.w };
                bf16x8 hh, ll;
                #pragma unroll
                for (int j = 0; j < 8; ++j) {
                    u16 h, l;
                    split2(fv[j], h, l);
                    hh[j] = (short)h; ll[j] = (short)l;
                }
                rh[nt][ks] = hh; rl[nt][ks] = ll;
            }
        __syncthreads();   // cbn_lds visible

        float m1[4], m2v[4];
        int   k1[4], k2[4];
        #pragma unroll
        for (int nt = 0; nt < 4; ++nt) { m1[nt] = 3.4e38f; m2v[nt] = 3.4e38f; k1[nt] = 0; k2[nt] = 0; }

        const int klo = w * 16 + lg * 4;
        for (int c = 0; c < 16; ++c) {
            int cbase = c * 64 + w * 16;
            // CB frags (A-operand) straight from global: code = cbase+lm
            bf16x8 ah[4], al[4];
            size_t gb = ((size_t)q * 1024 + cbase + lm) * 128 + lg * 8;
            #pragma unroll
            for (int ks = 0; ks < 4; ++ks) {
                ah[ks] = *(const bf16x8*)(CBh + gb + ks * 32);
                al[ks] = *(const bf16x8*)(CBl + gb + ks * 32);
            }
            float4 cbn4 = *(const float4*)&cbn_lds[cbase + lg * 4];

            #pragma unroll
            for (int nt = 0; nt < 4; ++nt) {
                f32x4 acc = (f32x4){0.f, 0.f, 0.f, 0.f};
                #pragma unroll
                for (int ks = 0; ks < 4; ++ks) {
                    acc = __builtin_amdgcn_mfma_f32_16x16x32_bf16(ah[ks], rh[nt][ks], acc, 0, 0, 0);
                    acc = __builtin_amdgcn_mfma_f32_16x16x32_bf16(ah[ks], rl[nt][ks], acc, 0, 0, 0);
                    acc = __builtin_amdgcn_mfma_f32_16x16x32_bf16(al[ks], rh[nt][ks], acc, 0, 0, 0);
                }
                float cbn_a[4] = { cbn4.x, cbn4.y, cbn4.z, cbn4.w };
                #pragma unroll
                for (int r = 0; r < 4; ++r) {
                    float d = fmaf(-2.f, acc[r], cbn_a[r]);
                    int  kk = c * 64 + klo + r;
                    bool lt1 = d < m1[nt];
                    bool lt2 = d < m2v[nt];
                    float nm2 = lt1 ? m1[nt] : (lt2 ? d : m2v[nt]);
                    int   nk2 = lt1 ? k1[nt] : (lt2 ? kk : k2[nt]);
                    if (lt1) { m1[nt] = d; k1[nt] = kk; }
                    m2v[nt] = nm2; k2[nt] = nk2;
                }
            }
        }

        // in-wave reduce across lg groups (xor 16, 32)
        #pragma unroll
        for (int nt = 0; nt < 4; ++nt) {
            #pragma unroll
            for (int st = 0; st < 2; ++st) {
                int msk = 16 << st;
                float om1 = __shfl_xor(m1[nt], msk);
                int   ok1 = __shfl_xor(k1[nt], msk);
                float om2 = __shfl_xor(m2v[nt], msk);
                int   ok2 = __shfl_xor(k2[nt], msk);
                bool aw = (m1[nt] < om1) || (m1[nt] == om1 && k1[nt] < ok1);
                float w1 = aw ? m1[nt] : om1;  int wk1 = aw ? k1[nt] : ok1;
                float l1 = aw ? om1 : m1[nt];  int lk1 = aw ? ok1 : k1[nt];
                float s2 = aw ? m2v[nt] : om2; int sk2 = aw ? k2[nt] : ok2;
                if (l1 < s2 || (l1 == s2 && lk1 < sk2)) { s2 = l1; sk2 = lk1; }
                m1[nt] = w1; k1[nt] = wk1; m2v[nt] = s2; k2[nt] = sk2;
            }
        }
        if (lane < 16) {
            #pragma unroll
            for (int nt = 0; nt < 4; ++nt) {
                int o = w * 64 + nt * 16 + lm;
                red_m1[o] = m1[nt]; red_k1[o] = k1[nt];
                red_m2[o] = m2v[nt]; red_k2[o] = k2[nt];
            }
        }
        __syncthreads();

        if (t < 64) {
            float M1 = 3.4e38f, M2 = 3.4e38f;
            int   K1 = 0x7fffffff, K2 = 0x7fffffff;
            #pragma unroll
            for (int ww = 0; ww < 4; ++ww) {
                int o = ww * 64 + t;
                float a1 = red_m1[o]; int b1 = red_k1[o];
                float a2 = red_m2[o]; int b2 = red_k2[o];
                if (a1 < M1 || (a1 == M1 && b1 < K1)) {
                    M2 = M1; K2 = K1; M1 = a1; K1 = b1;
                } else if (a1 < M2 || (a1 == M2 && b1 < K2)) { M2 = a1; K2 = b1; }
                if (a2 < M2 || (a2 == M2 && b2 < K2)) { M2 = a2; K2 = b2; }
            }
            int pick = K1;
            if (M2 - M1 <= RVQ_EPS) {
                // exact fp32 re-check of the two candidates
                const float* rrow = &r_lds[t * 132];
                float d1 = cbn_lds[K1] - 2.f * dot128(rrow, cbf + ((size_t)q * 1024 + K1) * 128);
                float d2 = cbn_lds[K2] - 2.f * dot128(rrow, cbf + ((size_t)q * 1024 + K2) * 128);
                if (d2 < d1 || (d2 == d1 && K2 < K1)) pick = K2;
            }
            idx_sh[t] = pick;
        }
        __syncthreads();

        // r -= cbf[q][idx]  (exact fp32)
        #pragma unroll
        for (int jj = 0; jj < 8; ++jj) {
            int f   = t + 256 * jj;
            int row = f >> 5;
            int c4  = (f & 31) << 2;
            int k   = idx_sh[row];
            float4 v = *(const float4*)(cbf + ((size_t)q * 1024 + k) * 128 + c4);
            float4* rp = (float4*)&r_lds[row * 132 + c4];
            float4 rv = *rp;
            rv.x -= v.x; rv.y -= v.y; rv.z -= v.z; rv.w -= v.w;
            *rp = rv;
        }
        __syncthreads();
    }

    // zhat = z - r_final (in place)
    #pragma unroll
    for (int jj = 0; jj < 8; ++jj) {
        int f   = t + 256 * jj;
        int row = f >> 5;
        int c4  = (f & 31) << 2;
        float4 zv = *(const float4*)(z + (size_t)(rbase + row) * 128 + c4);
        float4 rv = *(float4*)&r_lds[row * 132 + c4];
        float4 o = make_float4(zv.x - rv.x, zv.y - rv.y, zv.z - rv.z, zv.w - rv.w);
        *(float4*)(zhat + (size_t)(rbase + row) * 128 + c4) = o;
    }
}

// ---------------------------------------------------------------------------
extern "C" void kernel_launch(void* const* d_in, const int* in_sizes, int n_in,
                              void* d_out, int out_size, void* d_ws, size_t ws_size,
                              hipStream_t stream)
{
    const float* s    = (const float*)d_in[0];
    const float* goal = (const float*)d_in[1];
    const float* Wp[9]  = { (const float*)d_in[2],  (const float*)d_in[4],  (const float*)d_in[6],
                            (const float*)d_in[8],  (const float*)d_in[10], (const float*)d_in[12],
                            (const float*)d_in[14], (const float*)d_in[16], (const float*)d_in[18] };
    const float* Bp[9]  = { (const float*)d_in[3],  (const float*)d_in[5],  (const float*)d_in[7],
                            (const float*)d_in[9],  (const float*)d_in[11], (const float*)d_in[13],
                            (const float*)d_in[15], (const float*)d_in[17], (const float*)d_in[19] };
    const float* cb   = (const float*)d_in[20];
    float* out = (float*)d_out;

    static const int WK[9] = { 256, 512, 512, 384, 512, 512, 384, 1024, 1024 };
    static const int WN[9] = { 512, 512, 128, 512, 512, 128, 1024, 1024, 32 };
    size_t woff[10]; woff[0] = 0;
    for (int i = 0; i < 9; ++i) woff[i + 1] = woff[i] + (size_t)WK[i] * WN[i]; // 2457600

    float* zp  = (float*)d_ws;                       // [N,128]
    float* zz  = zp + (size_t)NROWS * 128;           // [N,128]; zhat in-place
    float* cbn = zz + (size_t)NROWS * 128;           // [8192]
    u16*  Wth  = (u16*)(cbn + 8192);
    u16*  Wtl  = Wth + woff[9];
    u16*  CBh  = Wtl + woff[9];                      // [1048576]
    u16*  CBl  = CBh + 1048576;
    uintptr_t bA = ((uintptr_t)(CBl + 1048576) + 255) & ~(uintptr_t)255;
    float* bufA = (float*)bA;

    size_t used = (size_t)(bA - (uintptr_t)d_ws);
    size_t avail = (ws_size > used) ? (ws_size - used) : 0;
    size_t ch = avail / (2 * 1024 * sizeof(float));
    if (ch > NROWS) ch = NROWS;
    ch &= ~(size_t)127;
    if (ch < 128) ch = 128;
    const int CH = (int)ch;
    float* bufB = bufA + (size_t)CH * 1024;

    dim3 blk(256);

    cbnorm_kernel<<<32, blk, 0, stream>>>(cb, cbn);
    cbsplit<<<1024, blk, 0, stream>>>(cb, CBh, CBl);
    for (int i = 0; i < 9; ++i)
        wsplit<<<dim3(WN[i] / 32, WK[i] / 64), blk, 0, stream>>>(Wp[i], Wth + woff[i], Wtl + woff[i], WK[i], WN[i]);

    // prior + posterior, chunked
    for (int off = 0; off < NROWS; off += CH) {
        int rows = (NROWS - off) < CH ? (NROWS - off) : CH;
        int gy = rows / 128;
        const float* sC = s + (size_t)off * 256;
        const float* gC = goal + (size_t)off * 128;
        gemm3<4,4,2,2,1><<<dim3(4, gy), blk, 0, stream>>>(sC, 256, nullptr, 0, Wth + woff[0], Wtl + woff[0], Bp[0], bufA, 256, 512);
        gemm3<4,4,2,2,1><<<dim3(4, gy), blk, 0, stream>>>(bufA, 512, nullptr, 0, Wth + woff[1], Wtl + woff[1], Bp[1], bufB, 512, 512);
        gemm3<4,4,2,2,0><<<dim3(1, gy), blk, 0, stream>>>(bufB, 512, nullptr, 0, Wth + woff[2], Wtl + woff[2], Bp[2], zp + (size_t)off * 128, 512, 128);
        gemm3<4,4,2,2,1><<<dim3(4, gy), blk, 0, stream>>>(sC, 256, gC, 128, Wth + woff[3], Wtl + woff[3], Bp[3], bufA, 384, 512);
        gemm3<4,4,2,2,1><<<dim3(4, gy), blk, 0, stream>>>(bufA, 512, nullptr, 0, Wth + woff[4], Wtl + woff[4], Bp[4], bufB, 512, 512);
        gemm3<4,4,2,2,0><<<dim3(1, gy), blk, 0, stream>>>(bufB, 512, nullptr, 0, Wth + woff[5], Wtl + woff[5], Bp[5], zz + (size_t)off * 128, 512, 128);
    }

    rvq_mfma<<<NROWS / 64, blk, 0, stream>>>(zz, zp, cb, CBh, CBl, cbn, zz);

    // decoder, chunked
    for (int off = 0; off < NROWS; off += CH) {
        int rows = (NROWS - off) < CH ? (NROWS - off) : CH;
        int gy = rows / 128;
        const float* sC = s + (size_t)off * 256;
        const float* zC = zz + (size_t)off * 128;
        gemm3<4,4,2,2,1><<<dim3(8, gy), blk, 0, stream>>>(sC, 256, zC, 128, Wth + woff[6], Wtl + woff[6], Bp[6], bufA, 384, 1024);
        gemm3<4,4,2,2,1><<<dim3(8, gy), blk, 0, stream>>>(bufA, 1024, nullptr, 0, Wth + woff[7], Wtl + woff[7], Bp[7], bufB, 1024, 1024);
        gemm3<2,2,1,4,0><<<dim3(1, gy), blk, 0, stream>>>(bufB, 1024, nullptr, 0, Wth + woff[8], Wtl + woff[8], Bp[8], out + (size_t)off * 32, 1024, 32);
    }
}